// Round 2
// baseline (1257.873 us; speedup 1.0000x reference)
//
#include <hip/hip_runtime.h>

// Problem: B=16, N=128, C=256, H=8, D=32.  All I/O fp32.
#define SCALE 0.17677669529663687f   // 1/sqrt(32)

typedef __attribute__((ext_vector_type(8))) __bf16 bf16x8;
typedef __attribute__((ext_vector_type(8))) unsigned short u16x8;
typedef __attribute__((ext_vector_type(4))) float f32x4;

__device__ inline float bf2f(unsigned short s) {
    union { unsigned int u; float f; } x; x.u = ((unsigned int)s) << 16; return x.f;
}
__device__ inline unsigned short f2bf(float f) {
    union { float f; unsigned int u; } x; x.f = f;
    return (unsigned short)((x.u + 0x7fffu + ((x.u >> 16) & 1u)) >> 16);   // RTNE
}

// Stage a [rows x 64] f32 k-slice (row ld = 256 floats) into LDS as bf16.
// nch = rows*8 chunks of 8 elements; 512 threads.
__device__ inline void stage_cvt(const float* __restrict__ src, size_t row0, int kOff,
                                 int nch, unsigned short* __restrict__ lds, int tid)
{
    for (int c = tid; c < nch; c += 512) {
        const int row = c >> 3, c8 = c & 7;
        const float* g = src + (row0 + (size_t)row) * 256 + kOff + c8 * 8;
        const float4 a = *(const float4*)g;
        const float4 b = *(const float4*)(g + 4);
        u16x8 p;
        p[0] = f2bf(a.x); p[1] = f2bf(a.y); p[2] = f2bf(a.z); p[3] = f2bf(a.w);
        p[4] = f2bf(b.x); p[5] = f2bf(b.y); p[6] = f2bf(b.z); p[7] = f2bf(b.w);
        *(u16x8*)(lds + row * 64 + c8 * 8) = p;
    }
}

// ---- K1: q,k,v projections (q pre-scaled), fp32 -> ws ----
__global__ void __launch_bounds__(256) qkv_kernel(
    const float* __restrict__ node,
    const float* __restrict__ Wq, const float* __restrict__ bq,
    const float* __restrict__ Wk, const float* __restrict__ bk,
    const float* __restrict__ Wv, const float* __restrict__ bv,
    float* __restrict__ qs, float* __restrict__ kf, float* __restrict__ vf)
{
    const int row = blockIdx.x, t = threadIdx.x;
    __shared__ float x[256];
    x[t] = node[(size_t)row * 256 + t];
    __syncthreads();
    const float4* wq = (const float4*)(Wq + (size_t)t * 256);
    const float4* wk = (const float4*)(Wk + (size_t)t * 256);
    const float4* wv = (const float4*)(Wv + (size_t)t * 256);
    float dq = 0.f, dk = 0.f, dv = 0.f;
#pragma unroll 8
    for (int i = 0; i < 64; ++i) {
        const float x0 = x[4 * i], x1 = x[4 * i + 1], x2 = x[4 * i + 2], x3 = x[4 * i + 3];
        float4 a;
        a = wq[i]; dq += a.x * x0 + a.y * x1 + a.z * x2 + a.w * x3;
        a = wk[i]; dk += a.x * x0 + a.y * x1 + a.z * x2 + a.w * x3;
        a = wv[i]; dv += a.x * x0 + a.y * x1 + a.z * x2 + a.w * x3;
    }
    const size_t o = (size_t)row * 256 + t;
    qs[o] = (dq + bq[t]) * SCALE;
    kf[o] =  dk + bk[t];
    vf[o] =  dv + bv[t];
}

// ---- Fused: per (b,i) — GEMM1(+gating) -> LDS attn -> GEMM2 -> softmax/agg/proj ----
// LDS: attn_s[128*256]u16 | Bs[256*64]u16 | As[128*64]u16 | agg[256]f32  = 115712 B
__global__ void __launch_bounds__(512, 1) fused_kernel(
    const float* __restrict__ edge,
    const float* __restrict__ We,  const float* __restrict__ be,
    const float* __restrict__ Woe, const float* __restrict__ boe,
    const float* __restrict__ Won, const float* __restrict__ bon,
    const float* __restrict__ qs,  const float* __restrict__ kf,
    const float* __restrict__ vf,
    float* __restrict__ out_node, float* __restrict__ out_edge)
{
    extern __shared__ __align__(16) char smem[];
    unsigned short* attn_s = (unsigned short*)smem;              // 65536 B
    unsigned short* Bs     = (unsigned short*)(smem + 65536);    // 32768 B
    unsigned short* As     = (unsigned short*)(smem + 98304);    // 16384 B
    float*          agg    = (float*)(smem + 114688);            //  1024 B

    const int mtile = blockIdx.x;                 // b*128 + i
    const int tid = threadIdx.x, lane = tid & 63, wid = tid >> 6;
    const int wM = (wid >> 2) * 64;               // wave row base (j)
    const int wN = (wid & 3) * 64;                // wave col base (c)
    const int fr = lane & 15, fq = (lane >> 4) * 8, quad = (lane >> 4) * 4;
    const size_t rowA0 = (size_t)mtile * 128;
    const int b128 = (mtile >> 7) * 128;          // b*128 (node-row base)

    // ---------- Phase 1: attn_pre = edge @ We^T (+be), gated epilogue ----------
    f32x4 acc[4][4];
#pragma unroll
    for (int i = 0; i < 4; ++i)
#pragma unroll
        for (int j = 0; j < 4; ++j) acc[i][j] = (f32x4){0.f, 0.f, 0.f, 0.f};

    for (int kt = 0; kt < 4; ++kt) {
        __syncthreads();
        stage_cvt(edge, rowA0, kt * 64, 1024, As, tid);
        stage_cvt(We,   0,    kt * 64, 2048, Bs, tid);
        __syncthreads();
#pragma unroll
        for (int ks = 0; ks < 2; ++ks) {
            bf16x8 af[4], bb[4];
#pragma unroll
            for (int mb = 0; mb < 4; ++mb)
                af[mb] = *(const bf16x8*)(As + (wM + mb * 16 + fr) * 64 + ks * 32 + fq);
#pragma unroll
            for (int nb = 0; nb < 4; ++nb)
                bb[nb] = *(const bf16x8*)(Bs + (wN + nb * 16 + fr) * 64 + ks * 32 + fq);
#pragma unroll
            for (int mb = 0; mb < 4; ++mb)
#pragma unroll
                for (int nb = 0; nb < 4; ++nb)
                    acc[mb][nb] = __builtin_amdgcn_mfma_f32_16x16x32_bf16(af[mb], bb[nb], acc[mb][nb], 0, 0, 0);
        }
    }
    // epilogue: D row=(lane>>4)*4+r (=j within wave), col=lane&15 (=channel)
    {
        const float* qrow = qs + (size_t)mtile * 256;
#pragma unroll
        for (int nb = 0; nb < 4; ++nb) {
            const int gc = wN + nb * 16 + fr;
            const float qv  = qrow[gc];
            const float bev = be[gc];
#pragma unroll
            for (int mb = 0; mb < 4; ++mb) {
#pragma unroll
                for (int r = 0; r < 4; ++r) {
                    const int j = wM + mb * 16 + quad + r;
                    const float e  = acc[mb][nb][r] + bev;
                    const float kv = kf[(size_t)(b128 + j) * 256 + gc];
                    attn_s[j * 256 + gc] = f2bf(qv * kv * (e + 1.0f) * e);
                }
            }
        }
    }

    // ---------- Phase 2: edge_out = attn @ Woe^T + boe (fp32 out) ----------
    f32x4 acc2[4][4];
#pragma unroll
    for (int i = 0; i < 4; ++i)
#pragma unroll
        for (int j = 0; j < 4; ++j) acc2[i][j] = (f32x4){0.f, 0.f, 0.f, 0.f};

    for (int kt = 0; kt < 4; ++kt) {
        __syncthreads();                                  // attn_s complete / Bs free
        stage_cvt(Woe, 0, kt * 64, 2048, Bs, tid);
        __syncthreads();
#pragma unroll
        for (int ks = 0; ks < 2; ++ks) {
            bf16x8 af[4], bb[4];
#pragma unroll
            for (int mb = 0; mb < 4; ++mb)
                af[mb] = *(const bf16x8*)(attn_s + (wM + mb * 16 + fr) * 256 + kt * 64 + ks * 32 + fq);
#pragma unroll
            for (int nb = 0; nb < 4; ++nb)
                bb[nb] = *(const bf16x8*)(Bs + (wN + nb * 16 + fr) * 64 + ks * 32 + fq);
#pragma unroll
            for (int mb = 0; mb < 4; ++mb)
#pragma unroll
                for (int nb = 0; nb < 4; ++nb)
                    acc2[mb][nb] = __builtin_amdgcn_mfma_f32_16x16x32_bf16(af[mb], bb[nb], acc2[mb][nb], 0, 0, 0);
        }
    }
    {
#pragma unroll
        for (int nb = 0; nb < 4; ++nb) {
            const int gc = wN + nb * 16 + fr;
            const float bo = boe[gc];
#pragma unroll
            for (int mb = 0; mb < 4; ++mb) {
#pragma unroll
                for (int r = 0; r < 4; ++r) {
                    const int j = wM + mb * 16 + quad + r;
                    out_edge[((size_t)mtile * 128 + j) * 256 + gc] = acc2[mb][nb][r] + bo;
                }
            }
        }
    }

    // ---------- Phase 3: per-channel softmax over j, <a,v>, Won projection ----------
    __syncthreads();
    if (tid < 256) {
        const int t = tid;
        float m = -1e30f;
#pragma unroll 8
        for (int j = 0; j < 128; ++j) m = fmaxf(m, bf2f(attn_s[j * 256 + t]));
        float l = 0.f, av = 0.f;
#pragma unroll 4
        for (int j = 0; j < 128; ++j) {
            const float w = __expf(bf2f(attn_s[j * 256 + t]) - m);
            l  += w;
            av += w * vf[(size_t)(b128 + j) * 256 + t];
        }
        agg[t] = av / l;
    }
    __syncthreads();
    if (tid < 256) {
        const int t = tid;
        const float4* wr = (const float4*)(Won + (size_t)t * 256);
        float o = bon[t];
#pragma unroll 8
        for (int i = 0; i < 64; ++i) {
            const float4 a = wr[i];
            o += a.x * agg[4 * i] + a.y * agg[4 * i + 1] + a.z * agg[4 * i + 2] + a.w * agg[4 * i + 3];
        }
        out_node[(size_t)mtile * 256 + t] = o;
    }
}

extern "C" void kernel_launch(void* const* d_in, const int* in_sizes, int n_in,
                              void* d_out, int out_size, void* d_ws, size_t ws_size,
                              hipStream_t stream) {
    const float* node = (const float*)d_in[0];
    const float* edge = (const float*)d_in[1];
    const float* Wq   = (const float*)d_in[2];
    const float* bq   = (const float*)d_in[3];
    const float* Wk   = (const float*)d_in[4];
    const float* bk   = (const float*)d_in[5];
    const float* Wv   = (const float*)d_in[6];
    const float* bv   = (const float*)d_in[7];
    const float* We   = (const float*)d_in[8];
    const float* be   = (const float*)d_in[9];
    const float* Woe  = (const float*)d_in[10];
    const float* boe  = (const float*)d_in[11];
    const float* Won  = (const float*)d_in[12];
    const float* bon  = (const float*)d_in[13];

    float* out_node = (float*)d_out;                      // [2048][256]
    float* out_edge = out_node + (size_t)2048 * 256;      // [262144][256]

    // ws: qs, kf, vf fp32 [2048][256] each (6 MB total)
    float* qs = (float*)d_ws;
    float* kf = qs + (size_t)2048 * 256;
    float* vf = kf + (size_t)2048 * 256;

    static const int lds_bytes = 115712;
    hipFuncSetAttribute((const void*)fused_kernel,
                        hipFuncAttributeMaxDynamicSharedMemorySize, lds_bytes);

    hipLaunchKernelGGL(qkv_kernel, dim3(2048), dim3(256), 0, stream,
                       node, Wq, bq, Wk, bk, Wv, bv, qs, kf, vf);
    hipLaunchKernelGGL(fused_kernel, dim3(2048), dim3(512), lds_bytes, stream,
                       edge, We, be, Woe, boe, Won, bon, qs, kf, vf,
                       out_node, out_edge);
}

// Round 3
// 630.454 us; speedup vs baseline: 1.9952x; 1.9952x over previous
//
#include <hip/hip_runtime.h>

// Problem: B=16, N=128, C=256, H=8, D=32.  All I/O fp32.
#define SCALE 0.17677669529663687f   // 1/sqrt(32)

typedef __attribute__((ext_vector_type(8))) __bf16 bf16x8;
typedef __attribute__((ext_vector_type(8))) unsigned short u16x8;
typedef __attribute__((ext_vector_type(4))) float f32x4;

__device__ inline float bf2f(unsigned short s) {
    union { unsigned int u; float f; } x; x.u = ((unsigned int)s) << 16; return x.f;
}
__device__ inline unsigned short f2bf(float f) {
    union { float f; unsigned int u; } x; x.f = f;
    return (unsigned short)((x.u + 0x7fffu + ((x.u >> 16) & 1u)) >> 16);   // RTNE
}
__device__ inline u16x8 cvt8(float4 a, float4 b) {
    u16x8 p;
    p[0] = f2bf(a.x); p[1] = f2bf(a.y); p[2] = f2bf(a.z); p[3] = f2bf(a.w);
    p[4] = f2bf(b.x); p[5] = f2bf(b.y); p[6] = f2bf(b.z); p[7] = f2bf(b.w);
    return p;
}
// swizzled offsets (u16 units). 8-chunk rows (64 ch):
__device__ inline int offT(int row, int c8) { return row * 64 + ((c8 ^ row) & 7) * 8; }
// 32-chunk rows (attn, 256 ch): swizzle low 3 bits of chunk index only
__device__ inline int offAttn(int j, int c8) { return j * 256 + (((c8) & 24) | ((c8 ^ j) & 7)) * 8; }

// ---- prep: convert We/Woe f32 -> bf16, pre-arranged in swizzled k-tile layout ----
__global__ void __launch_bounds__(256) prep_kernel(
    const float* __restrict__ We, const float* __restrict__ Woe,
    unsigned short* __restrict__ pWe, unsigned short* __restrict__ pWoe)
{
    const int id = blockIdx.x * 256 + threadIdx.x;        // 0..16383
    const float* W = (id & 8192) ? Woe : We;
    unsigned short* P = (id & 8192) ? pWoe : pWe;
    const int rem = id & 8191;
    const int kt = rem >> 11, chunk = rem & 2047, row = chunk >> 3, c8 = chunk & 7;
    const float* s = W + row * 256 + kt * 64 + c8 * 8;
    *(u16x8*)(P + kt * 16384 + offT(row, c8)) = cvt8(*(const float4*)s, *(const float4*)(s + 4));
}

// ---- qkv: {q,k,v} = node @ W^T + b  via MFMA.  grid (16, 6) ----
__global__ void __launch_bounds__(256) qkv_kernel(
    const float* __restrict__ node,
    const float* __restrict__ Wq, const float* __restrict__ bq,
    const float* __restrict__ Wk, const float* __restrict__ bk,
    const float* __restrict__ Wv, const float* __restrict__ bv,
    float* __restrict__ qs, float* __restrict__ kf, float* __restrict__ vf)
{
    __shared__ __align__(16) unsigned short As[128 * 64], Bs[128 * 64];
    const int wsel = blockIdx.y >> 1;                 // 0=q 1=k 2=v
    const int halfn = (blockIdx.y & 1) * 128;         // output-channel half
    const float* W    = wsel == 0 ? Wq : (wsel == 1 ? Wk : Wv);
    const float* bias = wsel == 0 ? bq : (wsel == 1 ? bk : bv);
    float*       out  = wsel == 0 ? qs : (wsel == 1 ? kf : vf);
    const float scl = wsel == 0 ? SCALE : 1.0f;
    const int tid = threadIdx.x, lane = tid & 63, wid = tid >> 6;
    const int wM = (wid >> 1) * 64, wN = (wid & 1) * 64;
    const int fr = lane & 15, quad = lane >> 4;
    const size_t M0 = (size_t)blockIdx.x * 128;

    f32x4 acc[4][4];
#pragma unroll
    for (int i = 0; i < 4; ++i)
#pragma unroll
        for (int j = 0; j < 4; ++j) acc[i][j] = (f32x4){0.f, 0.f, 0.f, 0.f};

    for (int kt = 0; kt < 4; ++kt) {
        __syncthreads();
#pragma unroll
        for (int i = 0; i < 4; ++i) {
            const int c = tid + i * 256, row = c >> 3, c8 = c & 7;
            const float* sa = node + (M0 + row) * 256 + kt * 64 + c8 * 8;
            const float* sb = W + (size_t)(halfn + row) * 256 + kt * 64 + c8 * 8;
            *(u16x8*)(As + offT(row, c8)) = cvt8(*(const float4*)sa, *(const float4*)(sa + 4));
            *(u16x8*)(Bs + offT(row, c8)) = cvt8(*(const float4*)sb, *(const float4*)(sb + 4));
        }
        __syncthreads();
#pragma unroll
        for (int ks = 0; ks < 2; ++ks) {
            bf16x8 af[4], bb[4];
#pragma unroll
            for (int mb = 0; mb < 4; ++mb) {
                const int row = wM + mb * 16 + fr;
                af[mb] = *(const bf16x8*)(As + offT(row, ks * 4 + quad));
            }
#pragma unroll
            for (int nb = 0; nb < 4; ++nb) {
                const int row = wN + nb * 16 + fr;
                bb[nb] = *(const bf16x8*)(Bs + offT(row, ks * 4 + quad));
            }
#pragma unroll
            for (int mb = 0; mb < 4; ++mb)
#pragma unroll
                for (int nb = 0; nb < 4; ++nb)
                    acc[mb][nb] = __builtin_amdgcn_mfma_f32_16x16x32_bf16(af[mb], bb[nb], acc[mb][nb], 0, 0, 0);
        }
    }
#pragma unroll
    for (int nb = 0; nb < 4; ++nb) {
        const int gc = halfn + wN + nb * 16 + fr;
        const float bv_ = bias[gc];
#pragma unroll
        for (int mb = 0; mb < 4; ++mb)
#pragma unroll
            for (int r = 0; r < 4; ++r) {
                const int j = wM + mb * 16 + quad * 4 + r;
                out[(M0 + j) * 256 + gc] = (acc[mb][nb][r] + bv_) * scl;
            }
    }
}

// ---- won: out_node = agg @ Won^T + bon.  grid (16, 2) ----
__global__ void __launch_bounds__(256) won_kernel(
    const float* __restrict__ agg, const float* __restrict__ Won,
    const float* __restrict__ bon, float* __restrict__ out_node)
{
    __shared__ __align__(16) unsigned short As[128 * 64], Bs[128 * 64];
    const int halfn = blockIdx.y * 128;
    const int tid = threadIdx.x, lane = tid & 63, wid = tid >> 6;
    const int wM = (wid >> 1) * 64, wN = (wid & 1) * 64;
    const int fr = lane & 15, quad = lane >> 4;
    const size_t M0 = (size_t)blockIdx.x * 128;

    f32x4 acc[4][4];
#pragma unroll
    for (int i = 0; i < 4; ++i)
#pragma unroll
        for (int j = 0; j < 4; ++j) acc[i][j] = (f32x4){0.f, 0.f, 0.f, 0.f};

    for (int kt = 0; kt < 4; ++kt) {
        __syncthreads();
#pragma unroll
        for (int i = 0; i < 4; ++i) {
            const int c = tid + i * 256, row = c >> 3, c8 = c & 7;
            const float* sa = agg + (M0 + row) * 256 + kt * 64 + c8 * 8;
            const float* sb = Won + (size_t)(halfn + row) * 256 + kt * 64 + c8 * 8;
            *(u16x8*)(As + offT(row, c8)) = cvt8(*(const float4*)sa, *(const float4*)(sa + 4));
            *(u16x8*)(Bs + offT(row, c8)) = cvt8(*(const float4*)sb, *(const float4*)(sb + 4));
        }
        __syncthreads();
#pragma unroll
        for (int ks = 0; ks < 2; ++ks) {
            bf16x8 af[4], bb[4];
#pragma unroll
            for (int mb = 0; mb < 4; ++mb)
                af[mb] = *(const bf16x8*)(As + offT(wM + mb * 16 + fr, ks * 4 + quad));
#pragma unroll
            for (int nb = 0; nb < 4; ++nb)
                bb[nb] = *(const bf16x8*)(Bs + offT(wN + nb * 16 + fr, ks * 4 + quad));
#pragma unroll
            for (int mb = 0; mb < 4; ++mb)
#pragma unroll
                for (int nb = 0; nb < 4; ++nb)
                    acc[mb][nb] = __builtin_amdgcn_mfma_f32_16x16x32_bf16(af[mb], bb[nb], acc[mb][nb], 0, 0, 0);
        }
    }
#pragma unroll
    for (int nb = 0; nb < 4; ++nb) {
        const int gc = halfn + wN + nb * 16 + fr;
        const float bv_ = bon[gc];
#pragma unroll
        for (int mb = 0; mb < 4; ++mb)
#pragma unroll
            for (int r = 0; r < 4; ++r) {
                const int j = wM + mb * 16 + quad * 4 + r;
                out_node[(M0 + j) * 256 + gc] = acc[mb][nb][r] + bv_;
            }
    }
}

// ---- fused: per (b,i): GEMM1(+gating)->LDS attn -> GEMM2 -> softmax/agg ----
// LDS: attn_s 64K | As 16K (aliased as reduction scratch in phase 3) = 80K -> 2 blocks/CU
__global__ void __launch_bounds__(512, 4) fused_kernel(
    const float* __restrict__ edge,
    const unsigned short* __restrict__ pWe,  const float* __restrict__ be,
    const unsigned short* __restrict__ pWoe, const float* __restrict__ boe,
    const float* __restrict__ qs, const float* __restrict__ kf, const float* __restrict__ vf,
    float* __restrict__ aggout, float* __restrict__ out_edge)
{
    extern __shared__ __align__(16) char smem[];
    unsigned short* attn_s = (unsigned short*)smem;            // 65536 B
    unsigned short* As     = (unsigned short*)(smem + 65536);  // 16384 B
    float*          sred   = (float*)(smem + 65536);           // phase-3 scratch (aliases As)

    const int mtile = blockIdx.x;                 // b*128 + i
    const int tid = threadIdx.x, lane = tid & 63, wid = tid >> 6;
    const int wM = (wid >> 2) * 64;               // j rows
    const int wN = (wid & 3) * 64;                // channels
    const int fr = lane & 15, quad = lane >> 4;
    const size_t rowA0 = (size_t)mtile * 128;
    const int b128 = (mtile >> 7) * 128;

    // ---------- Phase 1: e = edge @ We^T (+be), gated epilogue -> attn_s ----------
    const int c0 = tid, c1 = tid + 512;           // this thread's two A-chunks
    const int r0 = c0 >> 3, e0 = c0 & 7, r1 = c1 >> 3, e1 = c1 & 7;
    float4 pa0a, pa0b, pa1a, pa1b;
    {
        const float* s0 = edge + (rowA0 + r0) * 256 + e0 * 8;
        const float* s1 = edge + (rowA0 + r1) * 256 + e1 * 8;
        pa0a = *(const float4*)s0; pa0b = *(const float4*)(s0 + 4);
        pa1a = *(const float4*)s1; pa1b = *(const float4*)(s1 + 4);
    }
    f32x4 acc[4][4];
#pragma unroll
    for (int i = 0; i < 4; ++i)
#pragma unroll
        for (int j = 0; j < 4; ++j) acc[i][j] = (f32x4){0.f, 0.f, 0.f, 0.f};

    for (int kt = 0; kt < 4; ++kt) {
        __syncthreads();                               // As free (prev MFMA done); drains prefetch
        *(u16x8*)(As + offT(r0, e0)) = cvt8(pa0a, pa0b);
        *(u16x8*)(As + offT(r1, e1)) = cvt8(pa1a, pa1b);
        __syncthreads();                               // As visible (cheap: nothing vm pending)
        if (kt < 3) {                                  // prefetch next tile AFTER barrier
            const float* s0 = edge + (rowA0 + r0) * 256 + (kt + 1) * 64 + e0 * 8;
            const float* s1 = edge + (rowA0 + r1) * 256 + (kt + 1) * 64 + e1 * 8;
            pa0a = *(const float4*)s0; pa0b = *(const float4*)(s0 + 4);
            pa1a = *(const float4*)s1; pa1b = *(const float4*)(s1 + 4);
        }
        const unsigned short* BW = pWe + kt * 16384;
#pragma unroll
        for (int ks = 0; ks < 2; ++ks) {
            bf16x8 af[4], bb[4];
#pragma unroll
            for (int mb = 0; mb < 4; ++mb)
                af[mb] = *(const bf16x8*)(As + offT(wM + mb * 16 + fr, ks * 4 + quad));
#pragma unroll
            for (int nb = 0; nb < 4; ++nb)
                bb[nb] = *(const bf16x8*)(BW + offT(wN + nb * 16 + fr, ks * 4 + quad));
#pragma unroll
            for (int mb = 0; mb < 4; ++mb)
#pragma unroll
                for (int nb = 0; nb < 4; ++nb)
                    acc[mb][nb] = __builtin_amdgcn_mfma_f32_16x16x32_bf16(af[mb], bb[nb], acc[mb][nb], 0, 0, 0);
        }
    }
    {   // gated epilogue -> swizzled attn_s
        const float* qrow = qs + (size_t)mtile * 256;
#pragma unroll
        for (int nb = 0; nb < 4; ++nb) {
            const int gc = wN + nb * 16 + fr;
            const float qv = qrow[gc], bev = be[gc];
            const int c8 = gc >> 3, cl = gc & 7;
#pragma unroll
            for (int mb = 0; mb < 4; ++mb)
#pragma unroll
                for (int r = 0; r < 4; ++r) {
                    const int j = wM + mb * 16 + quad * 4 + r;
                    const float e = acc[mb][nb][r] + bev;
                    const float kv = kf[(size_t)(b128 + j) * 256 + gc];
                    attn_s[offAttn(j, c8) + cl] = f2bf(qv * kv * (e + 1.0f) * e);
                }
        }
    }
    __syncthreads();                                   // attn_s complete

    // ---------- Phase 2: edge_out = attn @ Woe^T + boe (no barriers) ----------
    f32x4 acc2[4][4];
#pragma unroll
    for (int i = 0; i < 4; ++i)
#pragma unroll
        for (int j = 0; j < 4; ++j) acc2[i][j] = (f32x4){0.f, 0.f, 0.f, 0.f};

    for (int kt = 0; kt < 4; ++kt) {
        const unsigned short* BW = pWoe + kt * 16384;
#pragma unroll
        for (int ks = 0; ks < 2; ++ks) {
            bf16x8 af[4], bb[4];
#pragma unroll
            for (int mb = 0; mb < 4; ++mb) {
                const int row = wM + mb * 16 + fr;
                af[mb] = *(const bf16x8*)(attn_s + offAttn(row, kt * 8 + ks * 4 + quad));
            }
#pragma unroll
            for (int nb = 0; nb < 4; ++nb)
                bb[nb] = *(const bf16x8*)(BW + offT(wN + nb * 16 + fr, ks * 4 + quad));
#pragma unroll
            for (int mb = 0; mb < 4; ++mb)
#pragma unroll
                for (int nb = 0; nb < 4; ++nb)
                    acc2[mb][nb] = __builtin_amdgcn_mfma_f32_16x16x32_bf16(af[mb], bb[nb], acc2[mb][nb], 0, 0, 0);
        }
    }
#pragma unroll
    for (int nb = 0; nb < 4; ++nb) {
        const int gc = wN + nb * 16 + fr;
        const float bo = boe[gc];
#pragma unroll
        for (int mb = 0; mb < 4; ++mb)
#pragma unroll
            for (int r = 0; r < 4; ++r) {
                const int j = wM + mb * 16 + quad * 4 + r;
                out_edge[((size_t)mtile * 128 + j) * 256 + gc] = acc2[mb][nb][r] + bo;
            }
    }

    // ---------- Phase 3: per-channel softmax over j, <a,v> -> agg ----------
    const int c = tid & 255, hlf = tid >> 8;           // 512 threads: 2 halves of j
    const int cc8 = c >> 3, ccl = c & 7;
    float m = -1e30f;
#pragma unroll 8
    for (int j2 = 0; j2 < 64; ++j2) {
        const int j = hlf * 64 + j2;
        m = fmaxf(m, bf2f(attn_s[offAttn(j, cc8) + ccl]));
    }
    sred[hlf * 256 + c] = m;                           // As region: free since phase 1
    __syncthreads();
    const float M = fmaxf(sred[c], sred[256 + c]);
    float l = 0.f, av = 0.f;
#pragma unroll 4
    for (int j2 = 0; j2 < 64; ++j2) {
        const int j = hlf * 64 + j2;
        const float w = __expf(bf2f(attn_s[offAttn(j, cc8) + ccl]) - M);
        l += w;
        av += w * vf[(size_t)(b128 + j) * 256 + c];
    }
    float* sl = sred + 512; float* sav = sred + 1024;
    sl[hlf * 256 + c] = l; sav[hlf * 256 + c] = av;
    __syncthreads();
    if (tid < 256) {
        const float L = sl[c] + sl[256 + c], AV = sav[c] + sav[256 + c];
        aggout[(size_t)mtile * 256 + c] = AV / L;
    }
}

extern "C" void kernel_launch(void* const* d_in, const int* in_sizes, int n_in,
                              void* d_out, int out_size, void* d_ws, size_t ws_size,
                              hipStream_t stream) {
    const float* node = (const float*)d_in[0];
    const float* edge = (const float*)d_in[1];
    const float* Wq   = (const float*)d_in[2];
    const float* bq   = (const float*)d_in[3];
    const float* Wk   = (const float*)d_in[4];
    const float* bk   = (const float*)d_in[5];
    const float* Wv   = (const float*)d_in[6];
    const float* bv   = (const float*)d_in[7];
    const float* We   = (const float*)d_in[8];
    const float* be   = (const float*)d_in[9];
    const float* Woe  = (const float*)d_in[10];
    const float* boe  = (const float*)d_in[11];
    const float* Won  = (const float*)d_in[12];
    const float* bon  = (const float*)d_in[13];

    float* out_node = (float*)d_out;                      // [2048][256]
    float* out_edge = out_node + (size_t)2048 * 256;      // [262144][256]

    // ws: pWe 128K | pWoe 128K | qs(/agg) 2M | kf 2M | vf 2M  = 6.5 MB
    char* ws = (char*)d_ws;
    unsigned short* pWe  = (unsigned short*)ws;
    unsigned short* pWoe = (unsigned short*)(ws + 131072);
    float* qs = (float*)(ws + 262144);
    float* kf = qs + (size_t)2048 * 256;
    float* vf = kf + (size_t)2048 * 256;
    float* agg = qs;                                      // qs dead after fused phase 1

    static const int lds_bytes = 81920;
    hipFuncSetAttribute((const void*)fused_kernel,
                        hipFuncAttributeMaxDynamicSharedMemorySize, lds_bytes);

    hipLaunchKernelGGL(prep_kernel, dim3(64), dim3(256), 0, stream, We, Woe, pWe, pWoe);
    hipLaunchKernelGGL(qkv_kernel, dim3(16, 6), dim3(256), 0, stream,
                       node, Wq, bq, Wk, bk, Wv, bv, qs, kf, vf);
    hipLaunchKernelGGL(fused_kernel, dim3(2048), dim3(512), lds_bytes, stream,
                       edge, pWe, be, pWoe, boe, qs, kf, vf, agg, out_edge);
    hipLaunchKernelGGL(won_kernel, dim3(16, 2), dim3(256), 0, stream,
                       agg, Won, bon, out_node);
}